// Round 9
// baseline (239.226 us; speedup 1.0000x reference)
//
#include <hip/hip_runtime.h>

// Problem constants
constexpr int Bb = 16;      // batch
constexpr int Nn = 256;     // regions
constexpr int Hh = 768;     // hidden
constexpr int Pp = 2048;    // proj dim
constexpr int Rr = 3;       // relation types
constexpr int Mm = Bb * Nn; // 4096 flattened rows
constexpr int HA = 896;     // augmented hidden (768 + 1 bias row + pad)
constexpr int KA = 2080;    // augmented K for Bop GEMM (2048 + 32)
constexpr int JA = Rr * HA; // 2688

typedef __bf16 bf16_t;
typedef __bf16 bf16x8 __attribute__((ext_vector_type(8)));
typedef __bf16 bf16x4 __attribute__((ext_vector_type(4)));
typedef float  floatx4 __attribute__((ext_vector_type(4)));

// async global->LDS, 16B per lane; LDS dest = wave-uniform base + lane*16
__device__ __forceinline__ void gld_lds16(const void* g, void* l) {
    __builtin_amdgcn_global_load_lds(
        (__attribute__((address_space(1))) void*)g,
        (__attribute__((address_space(3))) void*)l,
        16, 0, 0);
}

// ---------------------------------------------------------------------------
// MEGA-PREP: one kernel fusing 5 independent streaming passes (block-range
// dispatch).  (Launch-count cut 9->5 in R8 was worth ~8 us.)
// ---------------------------------------------------------------------------
constexpr int CVT_BLOCKS  = (Rr * Pp * Pp / 8) / 256;  // 6144
constexpr int FAUG_BLOCKS = Mm * (HA / 4) / 256;       // 3584
constexpr int TW_BX = Pp / 32, TW_BY = HA / 32;        // 64 x 28 = 1792
constexpr int HW_BX = KA / 32, HW_BY = HA / 32;        // 65 x 28 = 1820
constexpr int FILL_BLOCKS = (Rr * HA + 255) / 256;     // 11
constexpr int PREP_BLOCKS = CVT_BLOCKS + FAUG_BLOCKS
                          + TW_BX * TW_BY + HW_BX * HW_BY + FILL_BLOCKS;

__global__ __launch_bounds__(256) void prep_all(
    const float* __restrict__ bil_W, bf16_t* __restrict__ bilWh,
    const float* __restrict__ F,     bf16_t* __restrict__ Faug,
    const float* __restrict__ tW, const float* __restrict__ bt, bf16_t* __restrict__ tWaug,
    const float* __restrict__ hW, const float* __restrict__ bh, bf16_t* __restrict__ hWaug,
    const float* __restrict__ bil_b, bf16_t* __restrict__ T1)
{
    __shared__ float t[32][33];
    int bid = blockIdx.x;
    const int tid = threadIdx.x;

    if (bid < CVT_BLOCKS) {             // ---- cvt_bilW ----
        const size_t i = (size_t)bid * 256 + tid;
        const float4 v0 = ((const float4*)bil_W)[2 * i];
        const float4 v1 = ((const float4*)bil_W)[2 * i + 1];
        bf16x8 o = { (bf16_t)v0.x, (bf16_t)v0.y, (bf16_t)v0.z, (bf16_t)v0.w,
                     (bf16_t)v1.x, (bf16_t)v1.y, (bf16_t)v1.z, (bf16_t)v1.w };
        ((bf16x8*)bilWh)[i] = o;
        return;
    }
    bid -= CVT_BLOCKS;

    if (bid < FAUG_BLOCKS) {            // ---- build_Faug ----
        const int idx = bid * 256 + tid;
        const int n = idx / (HA / 4), c4 = idx % (HA / 4);
        const int h = c4 * 4;
        bf16x4 o;
        if (h < Hh) {
            float4 v = *(const float4*)(F + (size_t)n * Hh + h);
            o = { (bf16_t)v.x, (bf16_t)v.y, (bf16_t)v.z, (bf16_t)v.w };
        } else {
            #pragma unroll
            for (int e = 0; e < 4; ++e) o[e] = (bf16_t)((h + e == Hh) ? 1.0f : 0.0f);
        }
        *(bf16x4*)(Faug + (size_t)n * HA + h) = o;
        return;
    }
    bid -= FAUG_BLOCKS;

    const int tx = tid & 31, ty = tid >> 5;    // 32x8 layout for transposes

    if (bid < TW_BX * TW_BY) {          // ---- build_tWaug ----
        const int q0 = (bid % TW_BX) * 32, j0 = (bid / TW_BX) * 32;
        #pragma unroll
        for (int s = 0; s < 4; ++s) {
            const int q = q0 + ty + s * 8, j = j0 + tx;
            t[ty + s * 8][tx] = (j < Hh) ? tW[(size_t)q * Hh + j] : 0.0f;
        }
        __syncthreads();
        #pragma unroll
        for (int s = 0; s < 4; ++s) {
            const int j = j0 + ty + s * 8, q = q0 + tx;
            float v = t[tx][ty + s * 8];
            if (j == Hh) v = bt[q];
            else if (j > Hh) v = 0.0f;
            tWaug[(size_t)j * Pp + q] = (bf16_t)v;
        }
        return;
    }
    bid -= TW_BX * TW_BY;

    if (bid < HW_BX * HW_BY) {          // ---- build_hWaug ----
        const int p0 = (bid % HW_BX) * 32, h0 = (bid / HW_BX) * 32;
        #pragma unroll
        for (int s = 0; s < 4; ++s) {
            const int p = p0 + ty + s * 8, h = h0 + tx;
            t[ty + s * 8][tx] = (p < Pp && h < Hh) ? hW[(size_t)p * Hh + h] : 0.0f;
        }
        __syncthreads();
        #pragma unroll
        for (int s = 0; s < 4; ++s) {
            const int h = h0 + ty + s * 8, p = p0 + tx;
            float v = t[tx][ty + s * 8];
            if (h == Hh) v = (p < Pp) ? bh[p] : (p == Pp ? 1.0f : 0.0f);
            else if (h > Hh) v = 0.0f;
            hWaug[(size_t)h * KA + p] = (bf16_t)v;
        }
        return;
    }
    bid -= HW_BX * HW_BY;

    {                                   // ---- fill_T1cols ----
        const int idx = bid * 256 + tid;
        if (idx >= Rr * HA) return;
        const int r = idx / HA, j = idx % HA;
        bf16_t* p = T1 + (size_t)r * HA * KA + (size_t)j * KA + Pp;
        p[0] = (bf16_t)(j == Hh ? bil_b[r] : 0.0f);
        #pragma unroll
        for (int e = 1; e < 32; ++e) p[e] = (bf16_t)0.0f;
    }
}

// ---------------------------------------------------------------------------
// SPLIT-K=2 128x128-tile bf16 NT GEMM for T1 (gated on ws_size).
// Model (R0-R8): time = staged_bytes / (rate(blocks/CU) * 256); rate ~17.7
// B/cyc at 2.6 blocks/CU, collapses below ~2.  128^2 raises AI 42.7->64
// FLOP/staged-byte (staged 516->344 MB) but alone gives 336 blocks (1.3/CU);
// split-K=2 restores 672 blocks at 2.6/CU.  kh=0 writes T1taug (cols 0..2047,
// disjoint from prep's bias stripe at 2048+), kh=1 writes P1; reduce_T1 adds.
// grid 672 linear; XCD swizzle (672 = 8*84): each XCD = one kh, 4 n-tiles.
// ---------------------------------------------------------------------------
__global__ __launch_bounds__(256) void gemm_nt_sk2(
    const bf16_t* __restrict__ A, int lda,            // tWaug
    const bf16_t* __restrict__ B, int ldb, size_t sB, // bilWh
    bf16_t* __restrict__ C0, int ldc0, size_t sC0,    // T1taug (kh=0)
    bf16_t* __restrict__ C1, int ldc1, size_t sC1)    // P1     (kh=1)
{
    const int orig = blockIdx.x;
    const int wgid = (orig & 7) * 84 + (orig >> 3);
    const int kh   = wgid / 336;              // K-half
    const int rest = wgid % 336;
    const int n0 = (rest / 21) * 128;
    const int mr = rest % 21;
    const int m0 = (mr / 3) * 128;
    const int r  = mr % 3;

    A += (size_t)(kh << 10);                  // col offset kh*1024
    B += (size_t)r * sB + (kh << 10);

    __shared__ bf16_t As[2][128 * 32];
    __shared__ bf16_t Bs[2][128 * 32];

    const int tid = threadIdx.x;
    const int w = tid >> 6;
    const int l = tid & 63;

    const int srow = (w << 4) + (l >> 2);
    const int scol = (l & 3) << 3;
    const bf16_t* ga0 = A + (size_t)(m0 + srow) * lda + scol;
    const bf16_t* ga1 = ga0 + (size_t)64 * lda;
    const bf16_t* gb0 = B + (size_t)(n0 + srow) * ldb + scol;
    const bf16_t* gb1 = gb0 + (size_t)64 * ldb;

    const int wm = (w >> 1) << 6;
    const int wn = (w & 1) << 6;
    const int fr = l & 15;
    const int fq = (l >> 4) << 3;

    floatx4 acc[4][4] = {};

    {
        char* a = (char*)As[0] + (w << 10);
        char* b = (char*)Bs[0] + (w << 10);
        gld_lds16(ga0, a); gld_lds16(ga1, a + 4096);
        gld_lds16(gb0, b); gld_lds16(gb1, b + 4096);
        ga0 += 32; ga1 += 32; gb0 += 32; gb1 += 32;
    }

    constexpr int steps = 1024 >> 5;   // 32
    for (int k = 0; k < steps; ++k) {
        __syncthreads();
        const int cur = k & 1;
        if (k + 1 < steps) {
            char* a = (char*)As[cur ^ 1] + (w << 10);
            char* b = (char*)Bs[cur ^ 1] + (w << 10);
            gld_lds16(ga0, a); gld_lds16(ga1, a + 4096);
            gld_lds16(gb0, b); gld_lds16(gb1, b + 4096);
            ga0 += 32; ga1 += 32; gb0 += 32; gb1 += 32;
        }

        bf16x8 a[4], b[4];
        #pragma unroll
        for (int i = 0; i < 4; ++i) {
            a[i] = *(const bf16x8*)&As[cur][(wm + i * 16 + fr) * 32 + fq];
            b[i] = *(const bf16x8*)&Bs[cur][(wn + i * 16 + fr) * 32 + fq];
        }
        #pragma unroll
        for (int i = 0; i < 4; ++i)
            #pragma unroll
            for (int j = 0; j < 4; ++j)
                acc[i][j] = __builtin_amdgcn_mfma_f32_16x16x32_bf16(a[i], b[j], acc[i][j], 0, 0, 0);
    }

    bf16_t* C  = kh ? (C1 + (size_t)r * sC1) : (C0 + (size_t)r * sC0);
    const int ldc = kh ? ldc1 : ldc0;
    const int em = m0 + wm + ((l >> 4) << 2);
    const int en = n0 + wn + (l & 15);
    #pragma unroll
    for (int j = 0; j < 4; ++j) {
        const int n = en + j * 16;
        #pragma unroll
        for (int i = 0; i < 4; ++i) {
            #pragma unroll
            for (int rg = 0; rg < 4; ++rg)
                C[(size_t)(em + i * 16 + rg) * ldc + n] = (bf16_t)(acc[i][j][rg]);
        }
    }
}

// ---------------------------------------------------------------------------
// reduce: T1taug[r][j][q] += P1[r][j][q]  (q < 2048).  33.6 MB traffic.
// grid 2688 x 256, 8 elems/thread, exact cover.
// ---------------------------------------------------------------------------
__global__ __launch_bounds__(256) void reduce_T1(
    bf16_t* __restrict__ T1, const bf16_t* __restrict__ P1)
{
    const int i = blockIdx.x * 256 + threadIdx.x;   // [0, 3*896*256)
    const int q8 = i & 255;
    const int j  = (i >> 8) % HA;
    const int r  = i / (256 * HA);
    bf16_t* t = T1 + (size_t)r * HA * KA + (size_t)j * KA + q8 * 8;
    const bf16_t* p = P1 + ((size_t)r * HA + j) * Pp + q8 * 8;
    bf16x8 a = *(const bf16x8*)t;
    bf16x8 b = *(const bf16x8*)p;
    #pragma unroll
    for (int e = 0; e < 8; ++e) a[e] = (bf16_t)((float)a[e] + (float)b[e]);
    *(bf16x8*)t = a;
}

// ---------------------------------------------------------------------------
// FALLBACK T1: 128(M)x64(N)-tile bf16 NT GEMM (R8 body, 47 us) — used when
// ws_size has no room for the split-K partial buffer.
// ---------------------------------------------------------------------------
__global__ __launch_bounds__(256) void gemm_nt_128x64(
    const bf16_t* __restrict__ A, int lda,
    const bf16_t* __restrict__ B, int ldb, size_t sB,
    bf16_t* __restrict__ C, int ldc, size_t sC, int K)
{
    const int orig = blockIdx.y * 21 + blockIdx.x;
    const int wgid = (orig & 7) * 84 + (orig >> 3);
    const int n0 = (wgid / 21) * 64;
    const int mr = wgid % 21;
    const int m0 = (mr / 3) * 128;
    const int r  = mr % 3;
    B += (size_t)r * sB;
    C += (size_t)r * sC;

    __shared__ bf16_t As[2][128 * 32];
    __shared__ bf16_t Bs[2][64 * 32];

    const int tid = threadIdx.x;
    const int w = tid >> 6;
    const int l = tid & 63;

    const bf16_t* ga0 = A + (size_t)(m0 + (w << 4) + (l >> 2)) * lda + ((l & 3) << 3);
    const bf16_t* ga1 = ga0 + (size_t)64 * lda;
    const bf16_t* gb = B + (size_t)(n0 + (tid >> 2)) * ldb + ((tid & 3) << 3);

    const int wm = (w >> 1) << 6;
    const int wn = (w & 1) << 5;
    const int fr = l & 15;
    const int fq = (l >> 4) << 3;

    floatx4 acc[4][2] = {};

    {
        gld_lds16(ga0, (char*)As[0] + (w << 10));
        gld_lds16(ga1, (char*)As[0] + 4096 + (w << 10));
        gld_lds16(gb,  (char*)Bs[0] + (w << 10));
        ga0 += 32; ga1 += 32; gb += 32;
    }

    const int steps = K >> 5;   // 64
    for (int k = 0; k < steps; ++k) {
        __syncthreads();
        const int cur = k & 1;
        if (k + 1 < steps) {
            gld_lds16(ga0, (char*)As[cur ^ 1] + (w << 10));
            gld_lds16(ga1, (char*)As[cur ^ 1] + 4096 + (w << 10));
            gld_lds16(gb,  (char*)Bs[cur ^ 1] + (w << 10));
            ga0 += 32; ga1 += 32; gb += 32;
        }

        bf16x8 a[4], b[2];
        #pragma unroll
        for (int i = 0; i < 4; ++i)
            a[i] = *(const bf16x8*)&As[cur][(wm + i * 16 + fr) * 32 + fq];
        #pragma unroll
        for (int j = 0; j < 2; ++j)
            b[j] = *(const bf16x8*)&Bs[cur][(wn + j * 16 + fr) * 32 + fq];
        #pragma unroll
        for (int i = 0; i < 4; ++i)
            #pragma unroll
            for (int j = 0; j < 2; ++j)
                acc[i][j] = __builtin_amdgcn_mfma_f32_16x16x32_bf16(a[i], b[j], acc[i][j], 0, 0, 0);
    }

    const int em = m0 + wm + ((l >> 4) << 2);
    const int en = n0 + wn + (l & 15);
    #pragma unroll
    for (int i = 0; i < 4; ++i)
        #pragma unroll
        for (int j = 0; j < 2; ++j)
            #pragma unroll
            for (int rg = 0; rg < 4; ++rg)
                C[(size_t)(em + i * 16 + rg) * ldc + en + j * 16] = (bf16_t)acc[i][j][rg];
}

// ---------------------------------------------------------------------------
// 64x64-tile bf16 NT GEMM, dbuf LDS (for Bop). R6 body: bijective XCD
// swizzle (588 = 8*73 + 4). grid (14, 14, 3).
// ---------------------------------------------------------------------------
__global__ __launch_bounds__(256) void gemm_nt_64(
    const bf16_t* __restrict__ A, int lda, size_t sA,
    const bf16_t* __restrict__ B, int ldb, size_t sB,
    bf16_t* __restrict__ C, int ldc, size_t sC, int K)
{
    const int orig = (blockIdx.z * 14 + blockIdx.y) * 14 + blockIdx.x;
    const int xcd = orig & 7, idx = orig >> 3;
    const int wgid = (xcd < 4 ? xcd * 74 : 296 + (xcd - 4) * 73) + idx;
    const int r    = wgid / 196;
    const int rest = wgid % 196;
    const int m0 = (rest / 14) * 64;
    const int n0 = (rest % 14) * 64;
    A += (size_t)r * sA;
    B += (size_t)r * sB;
    C += (size_t)r * sC;

    __shared__ bf16_t As[2][64 * 32];
    __shared__ bf16_t Bs[2][64 * 32];

    const int tid = threadIdx.x;
    const int w = tid >> 6;
    const int l = tid & 63;

    const bf16_t* ga = A + (size_t)(m0 + (tid >> 2)) * lda + ((tid & 3) << 3);
    const bf16_t* gb = B + (size_t)(n0 + (tid >> 2)) * ldb + ((tid & 3) << 3);

    const int wm = (w >> 1) << 5;
    const int wn = (w & 1) << 5;
    const int fr = l & 15;
    const int fq = (l >> 4) << 3;

    floatx4 acc[2][2] = {};

    {
        gld_lds16(ga, (char*)As[0] + (w << 10));
        gld_lds16(gb, (char*)Bs[0] + (w << 10));
        ga += 32; gb += 32;
    }

    const int steps = K >> 5;
    for (int k = 0; k < steps; ++k) {
        __syncthreads();
        const int cur = k & 1;
        if (k + 1 < steps) {
            gld_lds16(ga, (char*)As[cur ^ 1] + (w << 10));
            gld_lds16(gb, (char*)Bs[cur ^ 1] + (w << 10));
            ga += 32; gb += 32;
        }

        bf16x8 a[2], b[2];
        #pragma unroll
        for (int i = 0; i < 2; ++i) {
            a[i] = *(const bf16x8*)&As[cur][(wm + i * 16 + fr) * 32 + fq];
            b[i] = *(const bf16x8*)&Bs[cur][(wn + i * 16 + fr) * 32 + fq];
        }
        #pragma unroll
        for (int i = 0; i < 2; ++i)
            #pragma unroll
            for (int j = 0; j < 2; ++j)
                acc[i][j] = __builtin_amdgcn_mfma_f32_16x16x32_bf16(a[i], b[j], acc[i][j], 0, 0, 0);
    }

    const int em = m0 + wm + ((l >> 4) << 2);
    const int en = n0 + wn + (l & 15);
    #pragma unroll
    for (int i = 0; i < 2; ++i)
        #pragma unroll
        for (int j = 0; j < 2; ++j)
            #pragma unroll
            for (int rg = 0; rg < 4; ++rg)
                C[(size_t)(em + i * 16 + rg) * ldc + en + j * 16] = (bf16_t)acc[i][j][rg];
}

// ---------------------------------------------------------------------------
// 128x128-tile bf16 NT GEMM, dbuf LDS (for FG). R6 body: XCD swizzle
// (672 = 8*84). grid (21, 32).
// ---------------------------------------------------------------------------
__global__ __launch_bounds__(256) void gemm_nt_128(
    const bf16_t* __restrict__ A, int lda,
    const bf16_t* __restrict__ B, int ldb,
    bf16_t* __restrict__ C, int ldc, int K)
{
    const int orig = blockIdx.y * 21 + blockIdx.x;
    const int wgid = (orig & 7) * 84 + (orig >> 3);
    const int m0 = (wgid / 21) * 128;
    const int n0 = (wgid % 21) * 128;

    __shared__ bf16_t As[2][128 * 32];
    __shared__ bf16_t Bs[2][128 * 32];

    const int tid = threadIdx.x;
    const int w = tid >> 6;
    const int l = tid & 63;

    const int srow = (w << 4) + (l >> 2);
    const int scol = (l & 3) << 3;
    const bf16_t* ga0 = A + (size_t)(m0 + srow) * lda + scol;
    const bf16_t* ga1 = ga0 + (size_t)64 * lda;
    const bf16_t* gb0 = B + (size_t)(n0 + srow) * ldb + scol;
    const bf16_t* gb1 = gb0 + (size_t)64 * ldb;

    const int wm = (w >> 1) << 6;
    const int wn = (w & 1) << 6;
    const int fr = l & 15;
    const int fq = (l >> 4) << 3;

    floatx4 acc[4][4] = {};

    {
        char* a = (char*)As[0] + (w << 10);
        char* b = (char*)Bs[0] + (w << 10);
        gld_lds16(ga0, a); gld_lds16(ga1, a + 4096);
        gld_lds16(gb0, b); gld_lds16(gb1, b + 4096);
        ga0 += 32; ga1 += 32; gb0 += 32; gb1 += 32;
    }

    const int steps = K >> 5;
    for (int k = 0; k < steps; ++k) {
        __syncthreads();
        const int cur = k & 1;
        if (k + 1 < steps) {
            char* a = (char*)As[cur ^ 1] + (w << 10);
            char* b = (char*)Bs[cur ^ 1] + (w << 10);
            gld_lds16(ga0, a); gld_lds16(ga1, a + 4096);
            gld_lds16(gb0, b); gld_lds16(gb1, b + 4096);
            ga0 += 32; ga1 += 32; gb0 += 32; gb1 += 32;
        }

        bf16x8 a[4], b[4];
        #pragma unroll
        for (int i = 0; i < 4; ++i) {
            a[i] = *(const bf16x8*)&As[cur][(wm + i * 16 + fr) * 32 + fq];
            b[i] = *(const bf16x8*)&Bs[cur][(wn + i * 16 + fr) * 32 + fq];
        }
        #pragma unroll
        for (int i = 0; i < 4; ++i)
            #pragma unroll
            for (int j = 0; j < 4; ++j)
                acc[i][j] = __builtin_amdgcn_mfma_f32_16x16x32_bf16(a[i], b[j], acc[i][j], 0, 0, 0);
    }

    const int em = m0 + wm + ((l >> 4) << 2);
    const int en = n0 + wn + (l & 15);
    #pragma unroll
    for (int j = 0; j < 4; ++j) {
        const int n = en + j * 16;
        #pragma unroll
        for (int i = 0; i < 4; ++i) {
            #pragma unroll
            for (int rg = 0; rg < 4; ++rg)
                C[(size_t)(em + i * 16 + rg) * ldc + n] = (bf16_t)(acc[i][j][rg]);
        }
    }
}

// ---------------------------------------------------------------------------
// fused output GEMM, all 3 r per block, dbuf LDS, K=896, 512 threads.
// R6 body: XCD swizzle (256 = 8*32). grid (4, 4, 16).
// ---------------------------------------------------------------------------
__global__ __launch_bounds__(512) void gemm_out_fused(
    const bf16_t* __restrict__ FG,    // [Mm, JA]
    const bf16_t* __restrict__ FA,    // [Mm, HA]
    float* __restrict__ OUT)
{
    const int orig = (blockIdx.z * 4 + blockIdx.y) * 4 + blockIdx.x;
    const int wgid = (orig & 7) * 32 + (orig >> 3);
    const int b  = wgid >> 4;
    const int n0 = ((wgid >> 2) & 3) * 64;
    const int m0 = (wgid & 3) * 64;

    __shared__ bf16_t S[2][4][64 * 32];  // tiles 0..2 = FG r, 3 = Faug (32KB)

    const int tid = threadIdx.x;
    const int w = tid >> 6;      // 0..7
    const int l = tid & 63;

    const int srow = ((w & 3) << 4) + (l >> 2);
    const int scol = (l & 3) << 3;
    const int t0 = w >> 2;               // issue0 tile: FG r = 0/1
    const bf16_t* g0 = FG + (size_t)(b * Nn + n0 + srow) * JA + t0 * HA + scol;
    const bf16_t* g1 = (t0 == 0)
        ? FG + (size_t)(b * Nn + n0 + srow) * JA + 2 * HA + scol   // tile2: FG r=2
        : FA + (size_t)(b * Nn + m0 + srow) * HA + scol;           // tile3: Faug

    const int n_off = (w >> 2) << 5;     // 0/32
    const int m_off = (w & 3) << 4;      // 0/16/32/48
    const int fr = l & 15;
    const int fq = (l >> 4) << 3;

    floatx4 acc[Rr][2] = {};

    {
        char* base = (char*)&S[0][0][0];
        gld_lds16(g0, base + (w << 10));        g0 += 32;
        gld_lds16(g1, base + 8192 + (w << 10)); g1 += 32;
    }

    constexpr int STEPS = HA / 32; // 28
    for (int k = 0; k < STEPS; ++k) {
        __syncthreads();
        const int cur = k & 1;
        if (k + 1 < STEPS) {
            char* base = (char*)&S[cur ^ 1][0][0];
            gld_lds16(g0, base + (w << 10));        g0 += 32;
            gld_lds16(g1, base + 8192 + (w << 10)); g1 += 32;
        }

        bf16x8 t = *(const bf16x8*)&S[cur][3][(m_off + fr) * 32 + fq];
        #pragma unroll
        for (int r = 0; r < Rr; ++r) {
            #pragma unroll
            for (int i = 0; i < 2; ++i) {
                bf16x8 a = *(const bf16x8*)&S[cur][r][(n_off + i * 16 + fr) * 32 + fq];
                acc[r][i] = __builtin_amdgcn_mfma_f32_16x16x32_bf16(a, t, acc[r][i], 0, 0, 0);
            }
        }
    }

    const int en_ = n0 + n_off + ((l >> 4) << 2);
    const int em_ = m0 + m_off + (l & 15);
    #pragma unroll
    for (int i = 0; i < 2; ++i)
        #pragma unroll
        for (int rg = 0; rg < 4; ++rg) {
            const int n = en_ + i * 16 + rg;
            float* o = OUT + (((size_t)b * Nn + n) * Nn + em_) * Rr;
            #pragma unroll
            for (int r = 0; r < Rr; ++r)
                o[r] = acc[r][i][rg];
        }
}

extern "C" void kernel_launch(void* const* d_in, const int* in_sizes, int n_in,
                              void* d_out, int out_size, void* d_ws, size_t ws_size,
                              hipStream_t stream) {
    const float* features = (const float*)d_in[0]; // [16,256,768]
    const float* head_W   = (const float*)d_in[1]; // [2048,768]
    const float* head_b   = (const float*)d_in[2]; // [2048]
    const float* tail_W   = (const float*)d_in[3]; // [2048,768]
    const float* tail_b   = (const float*)d_in[4]; // [2048]
    const float* bil_W    = (const float*)d_in[5]; // [3,2048,2048]
    const float* bil_b    = (const float*)d_in[6]; // [3]
    float* out = (float*)d_out;                    // [16,256,256,3]

    // workspace layout (bf16), base 52.76 MB (same as R8).
    // Z region (26.84 MB) is time-shared:
    //   prep+T1: bilWh (25.17 MB) at Z[0..]
    //   Bop+:    Bop (4.82 MB) at Z[0..]
    //   FG+:     FG (22.02 MB) at Z[4.82MB..]
    // Split-K partial P1 (11.01 MB) appended past the base layout, used only
    // if ws_size has room.
    char* ws = (char*)d_ws;
    bf16_t* Faug   = (bf16_t*)ws;  ws += (size_t)Mm * HA * 2;       // 7.34 MB
    bf16_t* tWaug  = (bf16_t*)ws;  ws += (size_t)HA * Pp * 2;       // 3.67 MB
    bf16_t* hWaug  = (bf16_t*)ws;  ws += (size_t)HA * KA * 2;       // 3.73 MB
    bf16_t* T1taug = (bf16_t*)ws;  ws += (size_t)Rr * HA * KA * 2;  // 11.18 MB
    char*   Z      = ws;           ws += (size_t)26836992;          // 26.84 MB
    bf16_t* bilWh  = (bf16_t*)Z;
    bf16_t* Bop    = (bf16_t*)Z;
    bf16_t* FG     = (bf16_t*)(Z + (size_t)Rr * HA * HA * 2);
    bf16_t* P1     = (bf16_t*)ws;                                   // 11.01 MB
    const size_t needSK = (size_t)(ws - (char*)d_ws) + (size_t)Rr * HA * Pp * 2;
    const bool useSK = (ws_size >= needSK);

    // 0) fused prep (unchanged from R8)
    prep_all<<<PREP_BLOCKS, 256, 0, stream>>>(
        bil_W, bilWh, features, Faug,
        tail_W, tail_b, tWaug,
        head_W, head_b, hWaug,
        bil_b, T1taug);

    // 1) T1taug[r] [896, 2048(+32)] = tWaug [896,2048] @ bilWh[r]^T
    if (useSK) {
        // split-K=2 at 128x128: 672 blocks (2.6/CU), staged 344 MB (was 516)
        gemm_nt_sk2<<<dim3(672), 256, 0, stream>>>(
            tWaug, Pp,
            bilWh, Pp, (size_t)Pp * Pp,
            T1taug, KA, (size_t)HA * KA,
            P1, Pp, (size_t)HA * Pp);
        reduce_T1<<<dim3(Rr * HA * (Pp / 8) / 256), 256, 0, stream>>>(T1taug, P1);
    } else {
        gemm_nt_128x64<<<dim3(21, 32), 256, 0, stream>>>(
            tWaug, Pp,
            bilWh, Pp, (size_t)Pp * Pp,
            T1taug, KA, (size_t)HA * KA, Pp);
    }

    // 2) Bop[r] [896, 896] = T1taug[r] [896,2080] @ hWaug^T [896,2080]
    gemm_nt_64<<<dim3(HA / 64, HA / 64, Rr), 256, 0, stream>>>(
        T1taug, KA, (size_t)HA * KA,
        hWaug, KA, 0,
        Bop, HA, (size_t)HA * HA, KA);

    // 3) FG [4096, 2688] = Faug [4096,896] @ Bop^T [2688,896]
    gemm_nt_128<<<dim3(JA / 128, Mm / 128), 256, 0, stream>>>(
        Faug, HA,
        Bop, HA,
        FG, JA, HA);

    // 4) fused output GEMM over all r (K=896, biases already folded in)
    gemm_out_fused<<<dim3(Nn / 64, Nn / 64, Bb), 512, 0, stream>>>(FG, Faug, out);
}

// Round 10
// 231.891 us; speedup vs baseline: 1.0316x; 1.0316x over previous
//
#include <hip/hip_runtime.h>

// Problem constants
constexpr int Bb = 16;      // batch
constexpr int Nn = 256;     // regions
constexpr int Hh = 768;     // hidden
constexpr int Pp = 2048;    // proj dim
constexpr int Rr = 3;       // relation types
constexpr int Mm = Bb * Nn; // 4096 flattened rows
constexpr int HA = 896;     // augmented hidden (768 + 1 bias row + pad)
constexpr int KA = 2080;    // augmented K for Bop GEMM (2048 + 32)
constexpr int JA = Rr * HA; // 2688
constexpr int KF = 800;     // exact K for FG/out: Faug cols >=800 are zero

typedef __bf16 bf16_t;
typedef __bf16 bf16x8 __attribute__((ext_vector_type(8)));
typedef __bf16 bf16x4 __attribute__((ext_vector_type(4)));
typedef float  floatx4 __attribute__((ext_vector_type(4)));

// async global->LDS, 16B per lane; LDS dest = wave-uniform base + lane*16
__device__ __forceinline__ void gld_lds16(const void* g, void* l) {
    __builtin_amdgcn_global_load_lds(
        (__attribute__((address_space(1))) void*)g,
        (__attribute__((address_space(3))) void*)l,
        16, 0, 0);
}

// ---------------------------------------------------------------------------
// MEGA-PREP: one kernel fusing 5 independent streaming passes (block-range
// dispatch).  (Launch-count cut in R8 was worth ~8 us.)
// ---------------------------------------------------------------------------
constexpr int CVT_BLOCKS  = (Rr * Pp * Pp / 8) / 256;  // 6144
constexpr int FAUG_BLOCKS = Mm * (HA / 4) / 256;       // 3584
constexpr int TW_BX = Pp / 32, TW_BY = HA / 32;        // 64 x 28 = 1792
constexpr int HW_BX = KA / 32, HW_BY = HA / 32;        // 65 x 28 = 1820
constexpr int FILL_BLOCKS = (Rr * HA + 255) / 256;     // 11
constexpr int PREP_BLOCKS = CVT_BLOCKS + FAUG_BLOCKS
                          + TW_BX * TW_BY + HW_BX * HW_BY + FILL_BLOCKS;

__global__ __launch_bounds__(256) void prep_all(
    const float* __restrict__ bil_W, bf16_t* __restrict__ bilWh,
    const float* __restrict__ F,     bf16_t* __restrict__ Faug,
    const float* __restrict__ tW, const float* __restrict__ bt, bf16_t* __restrict__ tWaug,
    const float* __restrict__ hW, const float* __restrict__ bh, bf16_t* __restrict__ hWaug,
    const float* __restrict__ bil_b, bf16_t* __restrict__ T1)
{
    __shared__ float t[32][33];
    int bid = blockIdx.x;
    const int tid = threadIdx.x;

    if (bid < CVT_BLOCKS) {             // ---- cvt_bilW ----
        const size_t i = (size_t)bid * 256 + tid;
        const float4 v0 = ((const float4*)bil_W)[2 * i];
        const float4 v1 = ((const float4*)bil_W)[2 * i + 1];
        bf16x8 o = { (bf16_t)v0.x, (bf16_t)v0.y, (bf16_t)v0.z, (bf16_t)v0.w,
                     (bf16_t)v1.x, (bf16_t)v1.y, (bf16_t)v1.z, (bf16_t)v1.w };
        ((bf16x8*)bilWh)[i] = o;
        return;
    }
    bid -= CVT_BLOCKS;

    if (bid < FAUG_BLOCKS) {            // ---- build_Faug ----
        const int idx = bid * 256 + tid;
        const int n = idx / (HA / 4), c4 = idx % (HA / 4);
        const int h = c4 * 4;
        bf16x4 o;
        if (h < Hh) {
            float4 v = *(const float4*)(F + (size_t)n * Hh + h);
            o = { (bf16_t)v.x, (bf16_t)v.y, (bf16_t)v.z, (bf16_t)v.w };
        } else {
            #pragma unroll
            for (int e = 0; e < 4; ++e) o[e] = (bf16_t)((h + e == Hh) ? 1.0f : 0.0f);
        }
        *(bf16x4*)(Faug + (size_t)n * HA + h) = o;
        return;
    }
    bid -= FAUG_BLOCKS;

    const int tx = tid & 31, ty = tid >> 5;    // 32x8 layout for transposes

    if (bid < TW_BX * TW_BY) {          // ---- build_tWaug ----
        const int q0 = (bid % TW_BX) * 32, j0 = (bid / TW_BX) * 32;
        #pragma unroll
        for (int s = 0; s < 4; ++s) {
            const int q = q0 + ty + s * 8, j = j0 + tx;
            t[ty + s * 8][tx] = (j < Hh) ? tW[(size_t)q * Hh + j] : 0.0f;
        }
        __syncthreads();
        #pragma unroll
        for (int s = 0; s < 4; ++s) {
            const int j = j0 + ty + s * 8, q = q0 + tx;
            float v = t[tx][ty + s * 8];
            if (j == Hh) v = bt[q];
            else if (j > Hh) v = 0.0f;
            tWaug[(size_t)j * Pp + q] = (bf16_t)v;
        }
        return;
    }
    bid -= TW_BX * TW_BY;

    if (bid < HW_BX * HW_BY) {          // ---- build_hWaug ----
        const int p0 = (bid % HW_BX) * 32, h0 = (bid / HW_BX) * 32;
        #pragma unroll
        for (int s = 0; s < 4; ++s) {
            const int p = p0 + ty + s * 8, h = h0 + tx;
            t[ty + s * 8][tx] = (p < Pp && h < Hh) ? hW[(size_t)p * Hh + h] : 0.0f;
        }
        __syncthreads();
        #pragma unroll
        for (int s = 0; s < 4; ++s) {
            const int h = h0 + ty + s * 8, p = p0 + tx;
            float v = t[tx][ty + s * 8];
            if (h == Hh) v = (p < Pp) ? bh[p] : (p == Pp ? 1.0f : 0.0f);
            else if (h > Hh) v = 0.0f;
            hWaug[(size_t)h * KA + p] = (bf16_t)v;
        }
        return;
    }
    bid -= HW_BX * HW_BY;

    {                                   // ---- fill_T1cols ----
        const int idx = bid * 256 + tid;
        if (idx >= Rr * HA) return;
        const int r = idx / HA, j = idx % HA;
        bf16_t* p = T1 + (size_t)r * HA * KA + (size_t)j * KA + Pp;
        p[0] = (bf16_t)(j == Hh ? bil_b[r] : 0.0f);
        #pragma unroll
        for (int e = 1; e < 32; ++e) p[e] = (bf16_t)0.0f;
    }
}

// ---------------------------------------------------------------------------
// T1: 128(M)x64(N)-tile bf16 NT GEMM (proven 47 us — structural floor per
// R9's split-K falsifier). XCD swizzle 672 = 8*84.
// ---------------------------------------------------------------------------
__global__ __launch_bounds__(256) void gemm_nt_128x64(
    const bf16_t* __restrict__ A, int lda,
    const bf16_t* __restrict__ B, int ldb, size_t sB,
    bf16_t* __restrict__ C, int ldc, size_t sC, int K)
{
    const int orig = blockIdx.y * 21 + blockIdx.x;
    const int wgid = (orig & 7) * 84 + (orig >> 3);
    const int n0 = (wgid / 21) * 64;
    const int mr = wgid % 21;
    const int m0 = (mr / 3) * 128;
    const int r  = mr % 3;
    B += (size_t)r * sB;
    C += (size_t)r * sC;

    __shared__ bf16_t As[2][128 * 32];
    __shared__ bf16_t Bs[2][64 * 32];

    const int tid = threadIdx.x;
    const int w = tid >> 6;
    const int l = tid & 63;

    const bf16_t* ga0 = A + (size_t)(m0 + (w << 4) + (l >> 2)) * lda + ((l & 3) << 3);
    const bf16_t* ga1 = ga0 + (size_t)64 * lda;
    const bf16_t* gb = B + (size_t)(n0 + (tid >> 2)) * ldb + ((tid & 3) << 3);

    const int wm = (w >> 1) << 6;
    const int wn = (w & 1) << 5;
    const int fr = l & 15;
    const int fq = (l >> 4) << 3;

    floatx4 acc[4][2] = {};

    {
        gld_lds16(ga0, (char*)As[0] + (w << 10));
        gld_lds16(ga1, (char*)As[0] + 4096 + (w << 10));
        gld_lds16(gb,  (char*)Bs[0] + (w << 10));
        ga0 += 32; ga1 += 32; gb += 32;
    }

    const int steps = K >> 5;   // 64
    for (int k = 0; k < steps; ++k) {
        __syncthreads();
        const int cur = k & 1;
        if (k + 1 < steps) {
            gld_lds16(ga0, (char*)As[cur ^ 1] + (w << 10));
            gld_lds16(ga1, (char*)As[cur ^ 1] + 4096 + (w << 10));
            gld_lds16(gb,  (char*)Bs[cur ^ 1] + (w << 10));
            ga0 += 32; ga1 += 32; gb += 32;
        }

        bf16x8 a[4], b[2];
        #pragma unroll
        for (int i = 0; i < 4; ++i)
            a[i] = *(const bf16x8*)&As[cur][(wm + i * 16 + fr) * 32 + fq];
        #pragma unroll
        for (int j = 0; j < 2; ++j)
            b[j] = *(const bf16x8*)&Bs[cur][(wn + j * 16 + fr) * 32 + fq];
        #pragma unroll
        for (int i = 0; i < 4; ++i)
            #pragma unroll
            for (int j = 0; j < 2; ++j)
                acc[i][j] = __builtin_amdgcn_mfma_f32_16x16x32_bf16(a[i], b[j], acc[i][j], 0, 0, 0);
    }

    const int em = m0 + wm + ((l >> 4) << 2);
    const int en = n0 + wn + (l & 15);
    #pragma unroll
    for (int i = 0; i < 4; ++i)
        #pragma unroll
        for (int j = 0; j < 2; ++j)
            #pragma unroll
            for (int rg = 0; rg < 4; ++rg)
                C[(size_t)(em + i * 16 + rg) * ldc + en + j * 16] = (bf16_t)acc[i][j][rg];
}

// ---------------------------------------------------------------------------
// 64x64-tile bf16 NT GEMM, dbuf LDS (for Bop). Bijective XCD swizzle
// (588 = 8*73 + 4). grid (14, 14, 3).
// ---------------------------------------------------------------------------
__global__ __launch_bounds__(256) void gemm_nt_64(
    const bf16_t* __restrict__ A, int lda, size_t sA,
    const bf16_t* __restrict__ B, int ldb, size_t sB,
    bf16_t* __restrict__ C, int ldc, size_t sC, int K)
{
    const int orig = (blockIdx.z * 14 + blockIdx.y) * 14 + blockIdx.x;
    const int xcd = orig & 7, idx = orig >> 3;
    const int wgid = (xcd < 4 ? xcd * 74 : 296 + (xcd - 4) * 73) + idx;
    const int r    = wgid / 196;
    const int rest = wgid % 196;
    const int m0 = (rest / 14) * 64;
    const int n0 = (rest % 14) * 64;
    A += (size_t)r * sA;
    B += (size_t)r * sB;
    C += (size_t)r * sC;

    __shared__ bf16_t As[2][64 * 32];
    __shared__ bf16_t Bs[2][64 * 32];

    const int tid = threadIdx.x;
    const int w = tid >> 6;
    const int l = tid & 63;

    const bf16_t* ga = A + (size_t)(m0 + (tid >> 2)) * lda + ((tid & 3) << 3);
    const bf16_t* gb = B + (size_t)(n0 + (tid >> 2)) * ldb + ((tid & 3) << 3);

    const int wm = (w >> 1) << 5;
    const int wn = (w & 1) << 5;
    const int fr = l & 15;
    const int fq = (l >> 4) << 3;

    floatx4 acc[2][2] = {};

    {
        gld_lds16(ga, (char*)As[0] + (w << 10));
        gld_lds16(gb, (char*)Bs[0] + (w << 10));
        ga += 32; gb += 32;
    }

    const int steps = K >> 5;
    for (int k = 0; k < steps; ++k) {
        __syncthreads();
        const int cur = k & 1;
        if (k + 1 < steps) {
            gld_lds16(ga, (char*)As[cur ^ 1] + (w << 10));
            gld_lds16(gb, (char*)Bs[cur ^ 1] + (w << 10));
            ga += 32; gb += 32;
        }

        bf16x8 a[2], b[2];
        #pragma unroll
        for (int i = 0; i < 2; ++i) {
            a[i] = *(const bf16x8*)&As[cur][(wm + i * 16 + fr) * 32 + fq];
            b[i] = *(const bf16x8*)&Bs[cur][(wn + i * 16 + fr) * 32 + fq];
        }
        #pragma unroll
        for (int i = 0; i < 2; ++i)
            #pragma unroll
            for (int j = 0; j < 2; ++j)
                acc[i][j] = __builtin_amdgcn_mfma_f32_16x16x32_bf16(a[i], b[j], acc[i][j], 0, 0, 0);
    }

    const int em = m0 + wm + ((l >> 4) << 2);
    const int en = n0 + wn + (l & 15);
    #pragma unroll
    for (int i = 0; i < 2; ++i)
        #pragma unroll
        for (int j = 0; j < 2; ++j)
            #pragma unroll
            for (int rg = 0; rg < 4; ++rg)
                C[(size_t)(em + i * 16 + rg) * ldc + en + j * 16] = (bf16_t)acc[i][j][rg];
}

// ---------------------------------------------------------------------------
// 128x128-tile bf16 NT GEMM, dbuf LDS (for FG). XCD swizzle (672 = 8*84).
// Called with K=800: Faug cols >=800 are zero, Bop cols >=769 are zero ->
// exact with 25 steps instead of 28.
// ---------------------------------------------------------------------------
__global__ __launch_bounds__(256) void gemm_nt_128(
    const bf16_t* __restrict__ A, int lda,
    const bf16_t* __restrict__ B, int ldb,
    bf16_t* __restrict__ C, int ldc, int K)
{
    const int orig = blockIdx.y * 21 + blockIdx.x;
    const int wgid = (orig & 7) * 84 + (orig >> 3);
    const int m0 = (wgid / 21) * 128;
    const int n0 = (wgid % 21) * 128;

    __shared__ bf16_t As[2][128 * 32];
    __shared__ bf16_t Bs[2][128 * 32];

    const int tid = threadIdx.x;
    const int w = tid >> 6;
    const int l = tid & 63;

    const int srow = (w << 4) + (l >> 2);
    const int scol = (l & 3) << 3;
    const bf16_t* ga0 = A + (size_t)(m0 + srow) * lda + scol;
    const bf16_t* ga1 = ga0 + (size_t)64 * lda;
    const bf16_t* gb0 = B + (size_t)(n0 + srow) * ldb + scol;
    const bf16_t* gb1 = gb0 + (size_t)64 * ldb;

    const int wm = (w >> 1) << 6;
    const int wn = (w & 1) << 6;
    const int fr = l & 15;
    const int fq = (l >> 4) << 3;

    floatx4 acc[4][4] = {};

    {
        char* a = (char*)As[0] + (w << 10);
        char* b = (char*)Bs[0] + (w << 10);
        gld_lds16(ga0, a); gld_lds16(ga1, a + 4096);
        gld_lds16(gb0, b); gld_lds16(gb1, b + 4096);
        ga0 += 32; ga1 += 32; gb0 += 32; gb1 += 32;
    }

    const int steps = K >> 5;
    for (int k = 0; k < steps; ++k) {
        __syncthreads();
        const int cur = k & 1;
        if (k + 1 < steps) {
            char* a = (char*)As[cur ^ 1] + (w << 10);
            char* b = (char*)Bs[cur ^ 1] + (w << 10);
            gld_lds16(ga0, a); gld_lds16(ga1, a + 4096);
            gld_lds16(gb0, b); gld_lds16(gb1, b + 4096);
            ga0 += 32; ga1 += 32; gb0 += 32; gb1 += 32;
        }

        bf16x8 a[4], b[4];
        #pragma unroll
        for (int i = 0; i < 4; ++i) {
            a[i] = *(const bf16x8*)&As[cur][(wm + i * 16 + fr) * 32 + fq];
            b[i] = *(const bf16x8*)&Bs[cur][(wn + i * 16 + fr) * 32 + fq];
        }
        #pragma unroll
        for (int i = 0; i < 4; ++i)
            #pragma unroll
            for (int j = 0; j < 4; ++j)
                acc[i][j] = __builtin_amdgcn_mfma_f32_16x16x32_bf16(a[i], b[j], acc[i][j], 0, 0, 0);
    }

    const int em = m0 + wm + ((l >> 4) << 2);
    const int en = n0 + wn + (l & 15);
    #pragma unroll
    for (int j = 0; j < 4; ++j) {
        const int n = en + j * 16;
        #pragma unroll
        for (int i = 0; i < 4; ++i) {
            #pragma unroll
            for (int rg = 0; rg < 4; ++rg)
                C[(size_t)(em + i * 16 + rg) * ldc + n] = (bf16_t)(acc[i][j][rg]);
        }
    }
}

// ---------------------------------------------------------------------------
// fused output GEMM, RESTRUCTURED: 32n x 64m x 3r per block, 256 threads
// (4 waves), grid 512 linear = 2 blocks/CU — escapes the 1-block/CU 8-wave
// regime (R7: ~5.6 TB/s) into the proven 2+/CU regime (~11 TB/s).
// K=800 exact (Faug cols >=800 zero): 25 steps.
//   logits[b,n,m,r] = sum_h FG[b*Nn+n, r*HA+h] * Faug[b*Nn+m, h]
// LDS/buf 10 KB: FG r0@0, r1@2048, r2@4096, Faug(64 rows)@6144 (bytes).
// Staging = 2 full issues + 1 half issue (waves 0-1 only; wave-uniform).
// XCD swizzle 512 = 8*64: each XCD owns 2 consecutive b values.
// ---------------------------------------------------------------------------
__global__ __launch_bounds__(256) void gemm_out_fused(
    const bf16_t* __restrict__ FG,    // [Mm, JA]
    const bf16_t* __restrict__ FA,    // [Mm, HA]
    float* __restrict__ OUT)
{
    const int orig = blockIdx.x;
    const int wgid = (orig & 7) * 64 + (orig >> 3);
    const int b    = wgid >> 5;
    const int rest = wgid & 31;
    const int n0 = (rest >> 2) * 32;
    const int m0 = (rest & 3) * 64;

    __shared__ bf16_t S[2][5120];   // 10 KB per buf

    const int tid = threadIdx.x;
    const int w = tid >> 6;          // 0..3
    const int l = tid & 63;
    const int row16 = ((w & 1) << 4) + (l >> 2);   // 0..31 per wave-pair
    const int scol  = (l & 3) << 3;

    // issue0: FG r = w>>1 (r0: waves 0-1, r1: waves 2-3), rows n0+row16
    const bf16_t* g0 = FG + (size_t)(b * Nn + n0 + row16) * JA + (w >> 1) * HA + scol;
    // issue1: waves 0-1 -> FG r2 rows n0+row16; waves 2-3 -> Faug rows m0+row16
    const bf16_t* g1 = (w < 2)
        ? FG + (size_t)(b * Nn + n0 + row16) * JA + 2 * HA + scol
        : FA + (size_t)(b * Nn + m0 + row16) * HA + scol;
    // issue2 (waves 0-1 only): Faug rows m0+32+w*16+l/4
    const bf16_t* g2 = FA + (size_t)(b * Nn + m0 + 32 + (w << 4) + (l >> 2)) * HA + scol;

    const int fr = l & 15;
    const int fq = (l >> 4) << 3;
    const int nf = (w >> 1) << 4;    // wave n-offset: 0/16
    const int mf = (w & 1) << 5;     // wave m-offset: 0/32

    floatx4 acc[Rr][2] = {};

    {
        char* base = (char*)&S[0][0];
        gld_lds16(g0, base + (w << 10));
        gld_lds16(g1, base + 4096 + (w << 10));
        if (w < 2) gld_lds16(g2, base + 8192 + (w << 10));
        g0 += 32; g1 += 32; g2 += 32;
    }

    constexpr int STEPS = KF / 32;   // 25
    for (int k = 0; k < STEPS; ++k) {
        __syncthreads();
        const int cur = k & 1;
        if (k + 1 < STEPS) {
            char* base = (char*)&S[cur ^ 1][0];
            gld_lds16(g0, base + (w << 10));
            gld_lds16(g1, base + 4096 + (w << 10));
            if (w < 2) gld_lds16(g2, base + 8192 + (w << 10));
            g0 += 32; g1 += 32; g2 += 32;
        }

        bf16x8 fa[2];
        #pragma unroll
        for (int j = 0; j < 2; ++j)
            fa[j] = *(const bf16x8*)&S[cur][3072 + (mf + j * 16 + fr) * 32 + fq];
        #pragma unroll
        for (int r = 0; r < Rr; ++r) {
            bf16x8 a = *(const bf16x8*)&S[cur][r * 1024 + (nf + fr) * 32 + fq];
            #pragma unroll
            for (int j = 0; j < 2; ++j)
                acc[r][j] = __builtin_amdgcn_mfma_f32_16x16x32_bf16(a, fa[j], acc[r][j], 0, 0, 0);
        }
    }

    const int en = n0 + nf + ((l >> 4) << 2);
    const int em = m0 + mf + fr;
    #pragma unroll
    for (int j = 0; j < 2; ++j)
        #pragma unroll
        for (int rg = 0; rg < 4; ++rg) {
            float* o = OUT + (((size_t)b * Nn + en + rg) * Nn + em + j * 16) * Rr;
            #pragma unroll
            for (int r = 0; r < Rr; ++r)
                o[r] = acc[r][j][rg];
        }
}

extern "C" void kernel_launch(void* const* d_in, const int* in_sizes, int n_in,
                              void* d_out, int out_size, void* d_ws, size_t ws_size,
                              hipStream_t stream) {
    const float* features = (const float*)d_in[0]; // [16,256,768]
    const float* head_W   = (const float*)d_in[1]; // [2048,768]
    const float* head_b   = (const float*)d_in[2]; // [2048]
    const float* tail_W   = (const float*)d_in[3]; // [2048,768]
    const float* tail_b   = (const float*)d_in[4]; // [2048]
    const float* bil_W    = (const float*)d_in[5]; // [3,2048,2048]
    const float* bil_b    = (const float*)d_in[6]; // [3]
    float* out = (float*)d_out;                    // [16,256,256,3]

    // workspace layout (bf16), 52.76 MB (R8 layout).
    // Z region (26.84 MB) time-shared:
    //   prep+T1: bilWh (25.17 MB) at Z[0..]
    //   Bop+:    Bop (4.82 MB) at Z[0..]
    //   FG+:     FG (22.02 MB) at Z[4.82MB..]
    char* ws = (char*)d_ws;
    bf16_t* Faug   = (bf16_t*)ws;  ws += (size_t)Mm * HA * 2;       // 7.34 MB
    bf16_t* tWaug  = (bf16_t*)ws;  ws += (size_t)HA * Pp * 2;       // 3.67 MB
    bf16_t* hWaug  = (bf16_t*)ws;  ws += (size_t)HA * KA * 2;       // 3.73 MB
    bf16_t* T1taug = (bf16_t*)ws;  ws += (size_t)Rr * HA * KA * 2;  // 11.18 MB
    char*   Z      = ws;
    bf16_t* bilWh  = (bf16_t*)Z;
    bf16_t* Bop    = (bf16_t*)Z;
    bf16_t* FG     = (bf16_t*)(Z + (size_t)Rr * HA * HA * 2);

    // 0) fused prep
    prep_all<<<PREP_BLOCKS, 256, 0, stream>>>(
        bil_W, bilWh, features, Faug,
        tail_W, tail_b, tWaug,
        head_W, head_b, hWaug,
        bil_b, T1taug);

    // 1) T1taug[r] [896, 2048(+32)] = tWaug [896,2048] @ bilWh[r]^T
    gemm_nt_128x64<<<dim3(21, 32), 256, 0, stream>>>(
        tWaug, Pp,
        bilWh, Pp, (size_t)Pp * Pp,
        T1taug, KA, (size_t)HA * KA, Pp);

    // 2) Bop[r] [896, 896] = T1taug[r] [896,2080] @ hWaug^T [896,2080]
    gemm_nt_64<<<dim3(HA / 64, HA / 64, Rr), 256, 0, stream>>>(
        T1taug, KA, (size_t)HA * KA,
        hWaug, KA, 0,
        Bop, HA, (size_t)HA * HA, KA);

    // 3) FG [4096, 2688] = Faug [4096,896] @ Bop^T [2688,896], K=800 exact
    gemm_nt_128<<<dim3(JA / 128, Mm / 128), 256, 0, stream>>>(
        Faug, HA,
        Bop, HA,
        FG, JA, KF);

    // 4) fused output GEMM, 512 blocks x 256 thr (2 blocks/CU), K=800 exact
    gemm_out_fused<<<dim3(512), 256, 0, stream>>>(FG, Faug, out);
}